// Round 1
// baseline (280.029 us; speedup 1.0000x reference)
//
#include <hip/hip_runtime.h>
#include <math.h>

#define B_   4
#define C_   64
#define N_   4096
#define CQK_ 16

// ---------------- QKV 1x1-conv projection ----------------
// Q: [B][N][16]  (query-major, row of 16 contiguous)
// K: [B][16][N]  (j contiguous)
// V: [B][64][N]  (j contiguous)
__global__ __launch_bounds__(256) void qkv_proj(
    const float* __restrict__ x, const float* __restrict__ xrgb,
    const float* __restrict__ Wq, const float* __restrict__ bq,
    const float* __restrict__ Wk, const float* __restrict__ bk,
    const float* __restrict__ Wv, const float* __restrict__ bv,
    float* __restrict__ Qo, float* __restrict__ Ko, float* __restrict__ Vo)
{
    __shared__ float wl[CQK_ * C_];
    __shared__ float bl[CQK_];
    const int t = threadIdx.x;
    const int g = blockIdx.y;   // 0:Q 1:K 2..5:V quarters
    const int b = blockIdx.z;
    const int n = blockIdx.x * 256 + t;

    const float* Wsrc;
    const float* bsrc;
    const float* src;
    int o0 = 0;
    if (g == 0)      { Wsrc = Wq; bsrc = bq; src = xrgb; }
    else if (g == 1) { Wsrc = Wk; bsrc = bk; src = x; }
    else             { o0 = (g - 2) * 16; Wsrc = Wv + o0 * C_; bsrc = bv + o0; src = x; }

    #pragma unroll
    for (int u = 0; u < 4; ++u) wl[u * 256 + t] = Wsrc[u * 256 + t];
    if (t < CQK_) bl[t] = bsrc[t];
    __syncthreads();

    float acc[16];
    #pragma unroll
    for (int o = 0; o < 16; ++o) acc[o] = bl[o];

    const float* sp = src + (size_t)b * C_ * N_ + n;
    #pragma unroll 4
    for (int c = 0; c < C_; ++c) {
        const float xv = sp[(size_t)c * N_];
        #pragma unroll
        for (int o = 0; o < 16; ++o) acc[o] += wl[o * C_ + c] * xv;
    }

    if (g == 0) {
        float* qp = Qo + ((size_t)(b * N_ + n)) * CQK_;
        #pragma unroll
        for (int o = 0; o < 16; ++o) qp[o] = acc[o];
    } else if (g == 1) {
        #pragma unroll
        for (int o = 0; o < 16; ++o) Ko[(size_t)(b * CQK_ + o) * N_ + n] = acc[o];
    } else {
        #pragma unroll
        for (int o = 0; o < 16; ++o) Vo[(size_t)(b * C_ + o0 + o) * N_ + n] = acc[o];
    }
}

// ---------------- fused flash attention (fp32, 4x4 register blocking) ----------------
// block: 256 threads (tx = t&15 -> j/c dim, ty = t>>4 -> i dim), 64-query tile
// grid: (N/64, B)
__global__ __launch_bounds__(256) void flash_attn(
    const float* __restrict__ Q, const float* __restrict__ K,
    const float* __restrict__ V, const float* __restrict__ x,
    const float* __restrict__ lam, float* __restrict__ out)
{
    __shared__ float qT[CQK_][68];  // qT[c][i]   (pad 68 keeps float4 rows aligned)
    __shared__ float kT[CQK_][68];  // kT[c][j]
    __shared__ float vT[64][68];    // vT[j][c]
    __shared__ float ps[64][68];    // ps[j][i], reused as o_lds[c][i] in epilogue

    const int t  = threadIdx.x;
    const int tx = t & 15;
    const int ty = t >> 4;
    const int b  = blockIdx.y;
    const int i0 = blockIdx.x * 64;

    // load + transpose Q tile (64 queries x 16 ch)
    {
        const float4 qv = *((const float4*)(Q + (size_t)(b * N_ + i0) * CQK_) + t);
        const int qi = t >> 2, qc = (t & 3) * 4;
        qT[qc + 0][qi] = qv.x;
        qT[qc + 1][qi] = qv.y;
        qT[qc + 2][qi] = qv.z;
        qT[qc + 3][qi] = qv.w;
    }

    float m_run[4], l_run[4], oacc[4][4];
    #pragma unroll
    for (int ii = 0; ii < 4; ++ii) {
        m_run[ii] = -1e30f;
        l_run[ii] = 0.f;
        #pragma unroll
        for (int cc = 0; cc < 4; ++cc) oacc[ii][cc] = 0.f;
    }

    for (int jc = 0; jc < N_ / 64; ++jc) {
        const int j0 = jc * 64;

        // stage K chunk 16x64 (coalesced global, float4 LDS row store)
        {
            const int kc = t >> 4, kj = (t & 15) * 4;
            const float4 kv = *(const float4*)(K + (size_t)(b * CQK_ + kc) * N_ + j0 + kj);
            *(float4*)&kT[kc][kj] = kv;
        }
        // stage V chunk 64x64, transposed to vT[j][c]
        {
            const int vj = (t & 15) * 4;
            #pragma unroll
            for (int r = 0; r < 4; ++r) {
                const int vc = (t >> 4) + r * 16;
                const float4 vv = *(const float4*)(V + (size_t)(b * C_ + vc) * N_ + j0 + vj);
                vT[vj + 0][vc] = vv.x;
                vT[vj + 1][vc] = vv.y;
                vT[vj + 2][vc] = vv.z;
                vT[vj + 3][vc] = vv.w;
            }
        }
        __syncthreads();

        // energy e[ii][jj] = q(i)·k(j), inner K = 16
        float e[4][4];
        #pragma unroll
        for (int ii = 0; ii < 4; ++ii)
            #pragma unroll
            for (int jj = 0; jj < 4; ++jj) e[ii][jj] = 0.f;

        #pragma unroll 4
        for (int c = 0; c < CQK_; ++c) {
            const float4 qv = *(const float4*)&qT[c][ty * 4];
            const float4 kv = *(const float4*)&kT[c][tx * 4];
            const float qa[4] = {qv.x, qv.y, qv.z, qv.w};
            const float ka[4] = {kv.x, kv.y, kv.z, kv.w};
            #pragma unroll
            for (int ii = 0; ii < 4; ++ii)
                #pragma unroll
                for (int jj = 0; jj < 4; ++jj) e[ii][jj] += qa[ii] * ka[jj];
        }

        // online softmax over this 64-j chunk (row stats across 16 tx lanes)
        #pragma unroll
        for (int ii = 0; ii < 4; ++ii) {
            float tm = fmaxf(fmaxf(e[ii][0], e[ii][1]), fmaxf(e[ii][2], e[ii][3]));
            tm = fmaxf(tm, __shfl_xor(tm, 1));
            tm = fmaxf(tm, __shfl_xor(tm, 2));
            tm = fmaxf(tm, __shfl_xor(tm, 4));
            tm = fmaxf(tm, __shfl_xor(tm, 8));
            const float nm = fmaxf(m_run[ii], tm);
            const float sc = __expf(m_run[ii] - nm);
            float psum = 0.f;
            #pragma unroll
            for (int jj = 0; jj < 4; ++jj) {
                e[ii][jj] = __expf(e[ii][jj] - nm);
                psum += e[ii][jj];
            }
            psum += __shfl_xor(psum, 1);
            psum += __shfl_xor(psum, 2);
            psum += __shfl_xor(psum, 4);
            psum += __shfl_xor(psum, 8);
            l_run[ii] = l_run[ii] * sc + psum;
            m_run[ii] = nm;
            #pragma unroll
            for (int cc = 0; cc < 4; ++cc) oacc[ii][cc] *= sc;
        }

        // publish P transposed: ps[j][i]
        #pragma unroll
        for (int jj = 0; jj < 4; ++jj)
            *(float4*)&ps[tx * 4 + jj][ty * 4] =
                make_float4(e[0][jj], e[1][jj], e[2][jj], e[3][jj]);

        __syncthreads();

        // PV: oacc[ii][cc] += sum_j P[i][j] * V[c][j]  (uniform-row b128 reads)
        #pragma unroll 8
        for (int j = 0; j < 64; ++j) {
            const float4 pv = *(const float4*)&ps[j][ty * 4];
            const float4 vv = *(const float4*)&vT[j][tx * 4];
            const float pa[4] = {pv.x, pv.y, pv.z, pv.w};
            const float va[4] = {vv.x, vv.y, vv.z, vv.w};
            #pragma unroll
            for (int ii = 0; ii < 4; ++ii)
                #pragma unroll
                for (int cc = 0; cc < 4; ++cc) oacc[ii][cc] += pa[ii] * va[cc];
        }
        __syncthreads();
    }

    // epilogue: out = lam * (O / l) + x, transposed through LDS for coalesced stores
    const float la = lam[0];
    #pragma unroll
    for (int cc = 0; cc < 4; ++cc) {
        *(float4*)&ps[tx * 4 + cc][ty * 4] = make_float4(
            oacc[0][cc] / l_run[0], oacc[1][cc] / l_run[1],
            oacc[2][cc] / l_run[2], oacc[3][cc] / l_run[3]);
    }
    __syncthreads();
    {
        const int c = t >> 2, seg = t & 3;
        const float* xp = x + (size_t)(b * C_ + c) * N_ + i0;
        float* op = out + (size_t)(b * C_ + c) * N_ + i0;
        #pragma unroll
        for (int w = 0; w < 4; ++w) {
            const int i = seg * 16 + w * 4;
            const float4 ov = *(const float4*)&ps[c][i];
            const float4 xv = *(const float4*)(xp + i);
            const float4 res = make_float4(la * ov.x + xv.x, la * ov.y + xv.y,
                                           la * ov.z + xv.z, la * ov.w + xv.w);
            *(float4*)(op + i) = res;
        }
    }
}

extern "C" void kernel_launch(void* const* d_in, const int* in_sizes, int n_in,
                              void* d_out, int out_size, void* d_ws, size_t ws_size,
                              hipStream_t stream)
{
    const float* x    = (const float*)d_in[0];
    const float* xrgb = (const float*)d_in[1];
    const float* Wq   = (const float*)d_in[2];
    const float* bq   = (const float*)d_in[3];
    const float* Wk   = (const float*)d_in[4];
    const float* bk   = (const float*)d_in[5];
    const float* Wv   = (const float*)d_in[6];
    const float* bv   = (const float*)d_in[7];
    const float* lam  = (const float*)d_in[8];
    float* out = (float*)d_out;

    // workspace layout (fp32): Q 1MB | K 1MB | V 4MB  (total 6 MB, all fully
    // overwritten by qkv_proj before flash_attn reads them)
    float* Qw = (float*)d_ws;                                  // B*N*CQK
    float* Kw = Qw + (size_t)B_ * N_ * CQK_;                   // B*CQK*N
    float* Vw = Kw + (size_t)B_ * CQK_ * N_;                   // B*C*N

    qkv_proj<<<dim3(N_ / 256, 6, B_), 256, 0, stream>>>(
        x, xrgb, Wq, bq, Wk, bk, Wv, bv, Qw, Kw, Vw);

    flash_attn<<<dim3(N_ / 64, B_), 256, 0, stream>>>(Qw, Kw, Vw, x, lam, out);
}

// Round 2
// 81.640 us; speedup vs baseline: 3.4301x; 3.4301x over previous
//
#include <hip/hip_runtime.h>
#include <hip/hip_bf16.h>
#include <math.h>

#define B_   4
#define C_   64
#define N_   4096
#define CQK_ 16

typedef __attribute__((ext_vector_type(8))) short bf16x8;
typedef __attribute__((ext_vector_type(4))) float f32x4;

static __device__ inline ushort f2bf(float f) {
    __hip_bfloat16 h = __float2bfloat16(f);
    return *reinterpret_cast<ushort*>(&h);
}
static __device__ inline uint packbf(float a, float b) {
    return (uint)f2bf(a) | ((uint)f2bf(b) << 16);
}

// ---------------- QKV 1x1-conv projection (fp32 math, bf16 outputs) --------
// Q: [B][N][16] bf16 (query-major rows of 32B)
// K: [B][N][16] bf16 (key-major rows of 32B)
// V: [B][64][N] bf16 (j contiguous)
__global__ __launch_bounds__(256) void qkv_proj(
    const float* __restrict__ x, const float* __restrict__ xrgb,
    const float* __restrict__ Wq, const float* __restrict__ bq,
    const float* __restrict__ Wk, const float* __restrict__ bk,
    const float* __restrict__ Wv, const float* __restrict__ bv,
    ushort* __restrict__ Qo, ushort* __restrict__ Ko, ushort* __restrict__ Vo)
{
    __shared__ float wl[CQK_ * C_];
    __shared__ float bl[CQK_];
    const int t = threadIdx.x;
    const int g = blockIdx.y;   // 0:Q 1:K 2..5:V quarters
    const int b = blockIdx.z;
    const int n = blockIdx.x * 256 + t;

    const float* Wsrc;
    const float* bsrc;
    const float* src;
    int o0 = 0;
    if (g == 0)      { Wsrc = Wq; bsrc = bq; src = xrgb; }
    else if (g == 1) { Wsrc = Wk; bsrc = bk; src = x; }
    else             { o0 = (g - 2) * 16; Wsrc = Wv + o0 * C_; bsrc = bv + o0; src = x; }

    #pragma unroll
    for (int u = 0; u < 4; ++u) wl[u * 256 + t] = Wsrc[u * 256 + t];
    if (t < CQK_) bl[t] = bsrc[t];
    __syncthreads();

    float acc[16];
    #pragma unroll
    for (int o = 0; o < 16; ++o) acc[o] = bl[o];

    const float* sp = src + (size_t)b * C_ * N_ + n;
    #pragma unroll 4
    for (int c = 0; c < C_; ++c) {
        const float xv = sp[(size_t)c * N_];
        #pragma unroll
        for (int o = 0; o < 16; ++o) acc[o] += wl[o * C_ + c] * xv;
    }

    if (g <= 1) {
        uint4 w0, w1;
        w0.x = packbf(acc[0],  acc[1]);  w0.y = packbf(acc[2],  acc[3]);
        w0.z = packbf(acc[4],  acc[5]);  w0.w = packbf(acc[6],  acc[7]);
        w1.x = packbf(acc[8],  acc[9]);  w1.y = packbf(acc[10], acc[11]);
        w1.z = packbf(acc[12], acc[13]); w1.w = packbf(acc[14], acc[15]);
        ushort* p = (g == 0 ? Qo : Ko) + (size_t)(b * N_ + n) * 16;
        *(uint4*)p = w0;
        *(uint4*)(p + 8) = w1;
    } else {
        #pragma unroll
        for (int o = 0; o < 16; ++o)
            Vo[(size_t)(b * C_ + o0 + o) * N_ + n] = f2bf(acc[o]);
    }
}

// ---------------- fused flash attention (bf16 MFMA) ----------------
// block: 256 threads = 4 waves; wave w owns 16 queries (iq0 = blk*64 + w*16).
// Per 64-j chunk: S^T = mfma(K,Q) (j lands in C/D rows), online softmax
// in-register, P -> bf16 -> per-wave LDS, PV = mfma(V, P^T).
// K/Q fragments zero-pad k 16->32. All LDS rows padded so each 8-lane
// cluster of a b128 read covers all 32 banks.
__global__ __launch_bounds__(256) void flash_attn_mfma(
    const ushort* __restrict__ Qg, const ushort* __restrict__ Kg,
    const ushort* __restrict__ Vg, const float* __restrict__ x,
    const float* __restrict__ lam, float* __restrict__ out)
{
    __shared__ __align__(16) ushort Kl[64][24];      // [j][c], 48B rows
    __shared__ __align__(16) ushort Vl[64][72];      // [c][j], 144B rows
    __shared__ __align__(16) ushort Pl[4][16][72];   // per-wave [i][j]

    const int t    = threadIdx.x;
    const int w    = t >> 6;
    const int lane = t & 63;
    const int li   = lane & 15;
    const int g    = lane >> 4;
    const int b    = blockIdx.y;
    const int i0   = blockIdx.x * 64;
    const int iq0  = i0 + w * 16;

    const bf16x8 fz = {0, 0, 0, 0, 0, 0, 0, 0};
    const f32x4  cz = {0.f, 0.f, 0.f, 0.f};

    // Q fragment, hoisted (B operand: col=i=li, k=c=g*8+r; g>=2 -> zero pad)
    bf16x8 qf = fz;
    if (g < 2)
        qf = *(const bf16x8*)(Qg + ((size_t)(b * N_ + iq0 + li) * 16 + g * 8));

    float m_run = -1e30f, l_run = 0.f;
    f32x4 oacc[4];
    #pragma unroll
    for (int ct = 0; ct < 4; ++ct) oacc[ct] = cz;

    // staging decomposition (all 256 threads)
    const int kr = t >> 2, ks = (t & 3) * 4;         // K: 64 rows x 4 segs x 8B
    const int vr = t >> 2, vs = (t & 3) * 16;        // V: 64 rows x 4 segs x 32B
    const ushort* ksrc = Kg + (size_t)(b * N_) * 16 + kr * 16 + ks;
    const ushort* vsrc = Vg + (size_t)(b * C_ + vr) * N_ + vs;

    // prologue: fetch chunk 0
    ushort4 kreg = *(const ushort4*)(ksrc);
    uint4   vreg0 = *(const uint4*)(vsrc);
    uint4   vreg1 = *(const uint4*)(vsrc + 8);
    *(ushort4*)&Kl[kr][ks] = kreg;
    *(uint4*)&Vl[vr][vs] = vreg0;
    *(uint4*)&Vl[vr][vs + 8] = vreg1;

    for (int jc = 0; jc < N_ / 64; ++jc) {
        __syncthreads();   // staged chunk jc visible

        // prefetch chunk jc+1 into registers (latency hidden under compute)
        if (jc + 1 < N_ / 64) {
            const size_t jn = (size_t)(jc + 1) * 64;
            kreg  = *(const ushort4*)(ksrc + jn * 16);
            vreg0 = *(const uint4*)(vsrc + jn);
            vreg1 = *(const uint4*)(vsrc + jn + 8);
        }

        // ---- energy: S^T[j][i] = sum_c K[j][c] Q[i][c] ----
        f32x4 st[4];
        #pragma unroll
        for (int jt = 0; jt < 4; ++jt) {
            bf16x8 kf = *(const bf16x8*)&Kl[jt * 16 + li][(g & 1) * 8];
            kf = (g < 2) ? kf : fz;
            st[jt] = __builtin_amdgcn_mfma_f32_16x16x32_bf16(kf, qf, cz, 0, 0, 0);
        }

        // ---- online softmax (16 j-values per lane, query i = li) ----
        float m_c = -1e30f;
        #pragma unroll
        for (int jt = 0; jt < 4; ++jt)
            #pragma unroll
            for (int r = 0; r < 4; ++r) m_c = fmaxf(m_c, st[jt][r]);
        m_c = fmaxf(m_c, __shfl_xor(m_c, 16));
        m_c = fmaxf(m_c, __shfl_xor(m_c, 32));
        const float m_new = fmaxf(m_run, m_c);
        const float sc = __expf(m_run - m_new);
        float psum = 0.f;
        #pragma unroll
        for (int jt = 0; jt < 4; ++jt)
            #pragma unroll
            for (int r = 0; r < 4; ++r) {
                const float p = __expf(st[jt][r] - m_new);
                st[jt][r] = p;
                psum += p;
            }
        psum += __shfl_xor(psum, 16);
        psum += __shfl_xor(psum, 32);
        l_run = l_run * sc + psum;
        m_run = m_new;
        #pragma unroll
        for (int ct = 0; ct < 4; ++ct) {
            oacc[ct][0] *= sc; oacc[ct][1] *= sc;
            oacc[ct][2] *= sc; oacc[ct][3] *= sc;
        }

        // ---- P -> bf16 -> per-wave LDS (row i=li, col j from C/D map) ----
        #pragma unroll
        for (int jt = 0; jt < 4; ++jt) {
            uint2 pw;
            pw.x = packbf(st[jt][0], st[jt][1]);
            pw.y = packbf(st[jt][2], st[jt][3]);
            *(uint2*)&Pl[w][li][jt * 16 + g * 4] = pw;
        }

        // ---- PV: O^T[c][i] += sum_j V[c][j] P^T[j][i] ----
        bf16x8 pf0 = *(const bf16x8*)&Pl[w][li][g * 8];
        bf16x8 pf1 = *(const bf16x8*)&Pl[w][li][32 + g * 8];
        #pragma unroll
        for (int ct = 0; ct < 4; ++ct) {
            bf16x8 vf0 = *(const bf16x8*)&Vl[ct * 16 + li][g * 8];
            bf16x8 vf1 = *(const bf16x8*)&Vl[ct * 16 + li][32 + g * 8];
            oacc[ct] = __builtin_amdgcn_mfma_f32_16x16x32_bf16(vf0, pf0, oacc[ct], 0, 0, 0);
            oacc[ct] = __builtin_amdgcn_mfma_f32_16x16x32_bf16(vf1, pf1, oacc[ct], 0, 0, 0);
        }

        __syncthreads();   // all waves done reading Kl/Vl

        // write prefetched chunk jc+1 to LDS
        if (jc + 1 < N_ / 64) {
            *(ushort4*)&Kl[kr][ks] = kreg;
            *(uint4*)&Vl[vr][vs] = vreg0;
            *(uint4*)&Vl[vr][vs + 8] = vreg1;
        }
    }

    // ---- epilogue: out = lam * O / l + x ----
    const float inv = lam[0] / l_run;
    const int n = iq0 + li;
    #pragma unroll
    for (int ct = 0; ct < 4; ++ct)
        #pragma unroll
        for (int r = 0; r < 4; ++r) {
            const int c = ct * 16 + g * 4 + r;
            const size_t off = (size_t)(b * C_ + c) * N_ + n;
            out[off] = oacc[ct][r] * inv + x[off];
        }
}

extern "C" void kernel_launch(void* const* d_in, const int* in_sizes, int n_in,
                              void* d_out, int out_size, void* d_ws, size_t ws_size,
                              hipStream_t stream)
{
    const float* x    = (const float*)d_in[0];
    const float* xrgb = (const float*)d_in[1];
    const float* Wq   = (const float*)d_in[2];
    const float* bq   = (const float*)d_in[3];
    const float* Wk   = (const float*)d_in[4];
    const float* bk   = (const float*)d_in[5];
    const float* Wv   = (const float*)d_in[6];
    const float* bv   = (const float*)d_in[7];
    const float* lam  = (const float*)d_in[8];
    float* out = (float*)d_out;

    // workspace (bf16): Q 512KB | K 512KB | V 2MB — all fully overwritten
    ushort* Qw = (ushort*)d_ws;                       // [B][N][16]
    ushort* Kw = Qw + (size_t)B_ * N_ * CQK_;         // [B][N][16]
    ushort* Vw = Kw + (size_t)B_ * N_ * CQK_;         // [B][C][N]

    qkv_proj<<<dim3(N_ / 256, 6, B_), 256, 0, stream>>>(
        x, xrgb, Wq, bq, Wk, bk, Wv, bv, Qw, Kw, Vw);

    flash_attn_mfma<<<dim3(N_ / 64, B_), 256, 0, stream>>>(
        Qw, Kw, Vw, x, lam, out);
}

// Round 3
// 55.943 us; speedup vs baseline: 5.0056x; 1.4593x over previous
//
#include <hip/hip_runtime.h>
#include <hip/hip_bf16.h>
#include <math.h>

#define B_   4
#define C_   64
#define N_   4096
#define CQK_ 16
#define L2E  1.4426950408889634f

typedef __attribute__((ext_vector_type(8))) short bf16x8;
typedef __attribute__((ext_vector_type(4))) float f32x4;

static __device__ inline ushort f2bf(float f) {
    __hip_bfloat16 h = __float2bfloat16(f);
    return *reinterpret_cast<ushort*>(&h);
}
static __device__ inline uint packbf(float a, float b) {
    return (uint)f2bf(a) | ((uint)f2bf(b) << 16);
}

// ---------------- QKV 1x1-conv projection (fp32 math, bf16 outputs) --------
// Q: [B][N][16] bf16 (scaled by log2(e) so softmax can use raw exp2)
// K: [B][N][16] bf16
// V: [B][64][N] bf16
__global__ __launch_bounds__(128) void qkv_proj(
    const float* __restrict__ x, const float* __restrict__ xrgb,
    const float* __restrict__ Wq, const float* __restrict__ bq,
    const float* __restrict__ Wk, const float* __restrict__ bk,
    const float* __restrict__ Wv, const float* __restrict__ bv,
    ushort* __restrict__ Qo, ushort* __restrict__ Ko, ushort* __restrict__ Vo)
{
    __shared__ float wl[CQK_ * C_];
    __shared__ float bl[CQK_];
    const int t = threadIdx.x;
    const int g = blockIdx.y;   // 0:Q 1:K 2..5:V quarters
    const int b = blockIdx.z;
    const int n = blockIdx.x * 128 + t;

    const float* Wsrc;
    const float* bsrc;
    const float* src;
    int o0 = 0;
    if (g == 0)      { Wsrc = Wq; bsrc = bq; src = xrgb; }
    else if (g == 1) { Wsrc = Wk; bsrc = bk; src = x; }
    else             { o0 = (g - 2) * 16; Wsrc = Wv + o0 * C_; bsrc = bv + o0; src = x; }

    const float wsc = (g == 0) ? L2E : 1.0f;   // fold log2e into Q
    #pragma unroll
    for (int u = 0; u < 8; ++u) wl[u * 128 + t] = Wsrc[u * 128 + t] * wsc;
    if (t < CQK_) bl[t] = bsrc[t] * wsc;
    __syncthreads();

    float acc[16];
    #pragma unroll
    for (int o = 0; o < 16; ++o) acc[o] = bl[o];

    const float* sp = src + (size_t)b * C_ * N_ + n;
    #pragma unroll 16
    for (int c = 0; c < C_; ++c) {
        const float xv = sp[(size_t)c * N_];
        #pragma unroll
        for (int o = 0; o < 16; ++o) acc[o] += wl[o * C_ + c] * xv;
    }

    if (g <= 1) {
        uint4 w0, w1;
        w0.x = packbf(acc[0],  acc[1]);  w0.y = packbf(acc[2],  acc[3]);
        w0.z = packbf(acc[4],  acc[5]);  w0.w = packbf(acc[6],  acc[7]);
        w1.x = packbf(acc[8],  acc[9]);  w1.y = packbf(acc[10], acc[11]);
        w1.z = packbf(acc[12], acc[13]); w1.w = packbf(acc[14], acc[15]);
        ushort* p = (g == 0 ? Qo : Ko) + (size_t)(b * N_ + n) * 16;
        *(uint4*)p = w0;
        *(uint4*)(p + 8) = w1;
    } else {
        #pragma unroll
        for (int o = 0; o < 16; ++o)
            Vo[(size_t)(b * C_ + o0 + o) * N_ + n] = f2bf(acc[o]);
    }
}

// ---------------- fused flash attention, intra-block j-split ----------------
// 1024 threads = 16 waves: jg = w>>2 (4 j-groups, each owns N/4 keys and its
// own K/V LDS staging), wq = w&3 (4 query sub-tiles of 16). End: merge the 4
// partial (m,l,O) in LDS. Grid stays 256 blocks -> 16 waves/CU = 4/SIMD.
#define SMEM_BYTES 86016
__global__ __launch_bounds__(1024, 4) void flash_attn_mfma(
    const ushort* __restrict__ Qg, const ushort* __restrict__ Kg,
    const ushort* __restrict__ Vg, const float* __restrict__ x,
    const float* __restrict__ lam, float* __restrict__ out)
{
    __shared__ __align__(16) char smem[SMEM_BYTES];
    ushort* KL = (ushort*)smem;                 // [4][64][24]  12288 B
    ushort* VL = (ushort*)(smem + 12288);       // [4][64][72]  36864 B
    ushort* PL = (ushort*)(smem + 49152);       // [16][16][72] 36864 B
    // combine overlay (used only after the main loop's final barrier):
    float*  OC = (float*)smem;                  // [4 wq][4 jg][64 c][17 i]
    float*  MC = (float*)(smem + 69632);        // [4][4][16]
    float*  LC = (float*)(smem + 70656);        // [4][4][16]

    const int t    = threadIdx.x;
    const int w    = t >> 6;
    const int lane = t & 63;
    const int li   = lane & 15;
    const int g    = lane >> 4;
    const int jg   = w >> 2;       // j-group
    const int wq   = w & 3;        // query sub-tile
    const int b    = blockIdx.y;
    const int i0   = blockIdx.x * 64;
    const int iq0  = i0 + wq * 16;

    const bf16x8 fz = {0, 0, 0, 0, 0, 0, 0, 0};
    const f32x4  cz = {0.f, 0.f, 0.f, 0.f};

    // Q fragment (B operand: col=i=li, k=c=g*8+r; g>=2 zero-pads k 16->32)
    bf16x8 qf = fz;
    if (g < 2)
        qf = *(const bf16x8*)(Qg + ((size_t)(b * N_ + iq0 + li) * 16 + g * 8));

    float m_run = -1e30f, l_run = 0.f;
    f32x4 oacc[4];
    #pragma unroll
    for (int ct = 0; ct < 4; ++ct) oacc[ct] = cz;

    // staging: each j-group's 256 threads stage its own K/V chunk
    const int tg = t & 255;
    const int kr = tg >> 2, ks = (tg & 3) * 4;      // K: 64 rows x 4 segs x 8B
    const int vr = tg >> 2, vs = (tg & 3) * 16;     // V: 64 rows x 4 segs x 32B
    const size_t jbase = (size_t)jg * (N_ / 4);
    const ushort* ksrc = Kg + ((size_t)(b * N_) + jbase + kr) * 16 + ks;
    const ushort* vsrc = Vg + (size_t)(b * C_ + vr) * N_ + jbase + vs;
    ushort* klw = KL + (jg * 64 + kr) * 24 + ks;
    ushort* vlw = VL + (jg * 64 + vr) * 72 + vs;

    // prologue: stage chunk 0
    ushort4 kreg  = *(const ushort4*)(ksrc);
    uint4   vreg0 = *(const uint4*)(vsrc);
    uint4   vreg1 = *(const uint4*)(vsrc + 8);
    *(ushort4*)klw = kreg;
    *(uint4*)vlw = vreg0;
    *(uint4*)(vlw + 8) = vreg1;

    for (int jc = 0; jc < 16; ++jc) {
        __syncthreads();   // staged chunk jc visible

        if (jc + 1 < 16) {   // register prefetch of next chunk (T14)
            const size_t jn = (size_t)(jc + 1) * 64;
            kreg  = *(const ushort4*)(ksrc + jn * 16);
            vreg0 = *(const uint4*)(vsrc + jn);
            vreg1 = *(const uint4*)(vsrc + jn + 8);
        }

        // ---- energy: S^T[j][i] = sum_c K[j][c] Q[i][c] (log2-scaled) ----
        f32x4 st[4];
        #pragma unroll
        for (int jt = 0; jt < 4; ++jt) {
            bf16x8 kf = *(const bf16x8*)(KL + (jg * 64 + jt * 16 + li) * 24 + (g & 1) * 8);
            kf = (g < 2) ? kf : fz;
            st[jt] = __builtin_amdgcn_mfma_f32_16x16x32_bf16(kf, qf, cz, 0, 0, 0);
        }

        // ---- online softmax (exp2 domain), defer-rescale T13 ----
        float m_c = -1e30f;
        #pragma unroll
        for (int jt = 0; jt < 4; ++jt)
            #pragma unroll
            for (int r = 0; r < 4; ++r) m_c = fmaxf(m_c, st[jt][r]);
        m_c = fmaxf(m_c, __shfl_xor(m_c, 16));
        m_c = fmaxf(m_c, __shfl_xor(m_c, 32));
        if (__any(m_c > m_run + 8.f)) {
            const float m_new = fmaxf(m_run, m_c);
            const float sc = exp2f(m_run - m_new);
            l_run *= sc;
            #pragma unroll
            for (int ct = 0; ct < 4; ++ct) {
                oacc[ct][0] *= sc; oacc[ct][1] *= sc;
                oacc[ct][2] *= sc; oacc[ct][3] *= sc;
            }
            m_run = m_new;
        }
        float psum = 0.f;
        #pragma unroll
        for (int jt = 0; jt < 4; ++jt)
            #pragma unroll
            for (int r = 0; r < 4; ++r) {
                const float p = exp2f(st[jt][r] - m_run);
                st[jt][r] = p;
                psum += p;
            }
        psum += __shfl_xor(psum, 16);
        psum += __shfl_xor(psum, 32);
        l_run += psum;

        // ---- P -> bf16 -> per-wave LDS (row i=li, col j per C/D map) ----
        #pragma unroll
        for (int jt = 0; jt < 4; ++jt) {
            uint2 pw;
            pw.x = packbf(st[jt][0], st[jt][1]);
            pw.y = packbf(st[jt][2], st[jt][3]);
            *(uint2*)(PL + (w * 16 + li) * 72 + jt * 16 + g * 4) = pw;
        }

        // ---- PV: O^T[c][i] += sum_j V[c][j] P^T[j][i] ----
        bf16x8 pf0 = *(const bf16x8*)(PL + (w * 16 + li) * 72 + g * 8);
        bf16x8 pf1 = *(const bf16x8*)(PL + (w * 16 + li) * 72 + 32 + g * 8);
        #pragma unroll
        for (int ct = 0; ct < 4; ++ct) {
            bf16x8 vf0 = *(const bf16x8*)(VL + (jg * 64 + ct * 16 + li) * 72 + g * 8);
            bf16x8 vf1 = *(const bf16x8*)(VL + (jg * 64 + ct * 16 + li) * 72 + 32 + g * 8);
            oacc[ct] = __builtin_amdgcn_mfma_f32_16x16x32_bf16(vf0, pf0, oacc[ct], 0, 0, 0);
            oacc[ct] = __builtin_amdgcn_mfma_f32_16x16x32_bf16(vf1, pf1, oacc[ct], 0, 0, 0);
        }

        __syncthreads();   // all waves done reading KL/VL/PL

        if (jc + 1 < 16) {   // write prefetched chunk
            *(ushort4*)klw = kreg;
            *(uint4*)vlw = vreg0;
            *(uint4*)(vlw + 8) = vreg1;
        }
    }

    // ---- write partials into combine overlay ----
    #pragma unroll
    for (int ct = 0; ct < 4; ++ct)
        #pragma unroll
        for (int r = 0; r < 4; ++r)
            OC[((wq * 4 + jg) * 64 + ct * 16 + g * 4 + r) * 17 + li] = oacc[ct][r];
    if (g == 0) {
        MC[(wq * 4 + jg) * 16 + li] = m_run;
        LC[(wq * 4 + jg) * 16 + li] = l_run;
    }
    __syncthreads();

    // ---- merge 4 j-partials; wave (jg,wq) handles channels jg*16..+16 ----
    const float m0 = MC[(wq * 4 + 0) * 16 + li];
    const float m1 = MC[(wq * 4 + 1) * 16 + li];
    const float m2 = MC[(wq * 4 + 2) * 16 + li];
    const float m3 = MC[(wq * 4 + 3) * 16 + li];
    const float ms = fmaxf(fmaxf(m0, m1), fmaxf(m2, m3));
    const float w0 = exp2f(m0 - ms), w1 = exp2f(m1 - ms);
    const float w2 = exp2f(m2 - ms), w3 = exp2f(m3 - ms);
    const float lsum = w0 * LC[(wq * 4 + 0) * 16 + li] + w1 * LC[(wq * 4 + 1) * 16 + li]
                     + w2 * LC[(wq * 4 + 2) * 16 + li] + w3 * LC[(wq * 4 + 3) * 16 + li];
    const float inv = lam[0] / lsum;
    const int n = iq0 - wq * 16 + (wq * 16 + li);   // = i0 + wq*16 + li
    #pragma unroll
    for (int r = 0; r < 4; ++r) {
        const int c = jg * 16 + g * 4 + r;
        const float ov = w0 * OC[((wq * 4 + 0) * 64 + c) * 17 + li]
                       + w1 * OC[((wq * 4 + 1) * 64 + c) * 17 + li]
                       + w2 * OC[((wq * 4 + 2) * 64 + c) * 17 + li]
                       + w3 * OC[((wq * 4 + 3) * 64 + c) * 17 + li];
        const size_t off = (size_t)(b * C_ + c) * N_ + n;
        out[off] = ov * inv + x[off];
    }
}

extern "C" void kernel_launch(void* const* d_in, const int* in_sizes, int n_in,
                              void* d_out, int out_size, void* d_ws, size_t ws_size,
                              hipStream_t stream)
{
    const float* x    = (const float*)d_in[0];
    const float* xrgb = (const float*)d_in[1];
    const float* Wq   = (const float*)d_in[2];
    const float* bq   = (const float*)d_in[3];
    const float* Wk   = (const float*)d_in[4];
    const float* bk   = (const float*)d_in[5];
    const float* Wv   = (const float*)d_in[6];
    const float* bv   = (const float*)d_in[7];
    const float* lam  = (const float*)d_in[8];
    float* out = (float*)d_out;

    // workspace (bf16): Q 512KB | K 512KB | V 2MB — all fully overwritten
    ushort* Qw = (ushort*)d_ws;                       // [B][N][16]
    ushort* Kw = Qw + (size_t)B_ * N_ * CQK_;         // [B][N][16]
    ushort* Vw = Kw + (size_t)B_ * N_ * CQK_;         // [B][C][N]

    qkv_proj<<<dim3(N_ / 128, 6, B_), 128, 0, stream>>>(
        x, xrgb, Wq, bq, Wk, bk, Wv, bv, Qw, Kw, Vw);

    flash_attn_mfma<<<dim3(N_ / 64, B_), 1024, 0, stream>>>(
        Qw, Kw, Vw, x, lam, out);
}